// Round 18
// baseline (138.764 us; speedup 1.0000x reference)
//
#include <hip/hip_runtime.h>
#include <math.h>

#define FIN 128
#define H 64
#define FOUT 2
#define NEG_SLOPE 0.2f
#define EPS 1e-16f

#define SCAN_CHUNK 2048   // elements per scan_a block (256 thr * 8)

typedef __attribute__((ext_vector_type(8))) short s8v;   // 8 bf16 (4 VGPR)
typedef __attribute__((ext_vector_type(4))) float f4v;   // MFMA acc

// Preamble: exclusive scan of blocksum[0..nscan) into LDS bs[] (nscan <= 64).
__device__ __forceinline__ void load_bs(const int* __restrict__ blocksum, int nscan,
                                        int* bs, int tid){
  if(tid < 64){
    int v = (tid < nscan)? blocksum[tid] : 0;
    int incl = v;
    #pragma unroll
    for(int o=1;o<64;o<<=1){ int u=__shfl_up(incl,o); if(tid>=o) incl+=u; }
    bs[tid] = incl - v;
  }
  __syncthreads();
}

// K0: fused [zero degs (4 shards)] + [pack W into MFMA fragments, split hi/lo bf16].
__global__ void k_prep(int* __restrict__ degs, int N4, int ZB,
                       const float* __restrict__ Wl, const float* __restrict__ Wr,
                       unsigned short* __restrict__ pWh, unsigned short* __restrict__ pWe){
  int b = blockIdx.x;
  if(b < ZB){
    int i = b*256 + threadIdx.x;
    if(i < N4) degs[i] = 0;
    return;
  }
  int idx = (b - ZB)*256 + threadIdx.x;     // (ct*4+k0)*64 + lane, < 2048
  int lane = idx & 63;
  int ctk  = idx >> 6;
  int k0   = (ctk & 3) * 32;
  int ct   = ctk >> 2;
  int c    = ct*16 + (lane & 15);
  int kb   = k0 + (lane >> 4)*8;
  const float* Wp = (c < 64) ? (Wl + c) : (Wr + (c - 64));
  #pragma unroll
  for(int j=0;j<8;j++){
    float v = Wp[(size_t)(kb + j)*H];
    unsigned u = __float_as_uint(v);
    unsigned short hb = (unsigned short)(u >> 16);
    float hv = __uint_as_float(((unsigned)hb) << 16);
    float ev = v - hv;
    unsigned short eb = (unsigned short)(__float_as_uint(ev) >> 16);
    pWh[(size_t)idx*8 + j] = hb;
    pWe[(size_t)idx*8 + j] = eb;
  }
}

// K1: MFMA GEMM, swapped operands: D = W^T x; float4/ushort4 stores.
__global__ __launch_bounds__(256) void k_gemm_mfma(
    const float* __restrict__ x,
    const unsigned short* __restrict__ pWh, const unsigned short* __restrict__ pWe,
    float* __restrict__ xr, unsigned short* __restrict__ xlb, int N){
  int tid = threadIdx.x;
  int lane = tid & 63, wid = tid >> 6;
  int rowbase = blockIdx.x*64 + wid*16;
  int r = lane & 15, g = lane >> 4;

  int arow = rowbase + r; if(arow > N-1) arow = N-1;
  const float* xrow = x + (size_t)arow*FIN;
  int orow = rowbase + r;

  s8v xh[4], xe[4];
  #pragma unroll
  for(int k0=0;k0<4;k0++){
    float4 va = *(const float4*)(xrow + k0*32 + g*8);
    float4 vb = *(const float4*)(xrow + k0*32 + g*8 + 4);
    float xs_[8] = {va.x,va.y,va.z,va.w,vb.x,vb.y,vb.z,vb.w};
    #pragma unroll
    for(int j=0;j<8;j++){
      unsigned u = __float_as_uint(xs_[j]);
      unsigned short hb = (unsigned short)(u >> 16);
      xh[k0][j] = (short)hb;
      float ev = xs_[j] - __uint_as_float(((unsigned)hb) << 16);
      xe[k0][j] = (short)(unsigned short)(__float_as_uint(ev) >> 16);
    }
  }

  #pragma unroll 2
  for(int ct=0;ct<8;ct++){
    f4v a = (f4v){0.f,0.f,0.f,0.f};
    #pragma unroll
    for(int k0=0;k0<4;k0++){
      size_t boff = ((size_t)(ct*4 + k0)*64 + lane)*8;
      s8v wh = *(const s8v*)(pWh + boff);
      s8v we = *(const s8v*)(pWe + boff);
      a = __builtin_amdgcn_mfma_f32_16x16x32_bf16(wh, xh[k0], a, 0,0,0);
      a = __builtin_amdgcn_mfma_f32_16x16x32_bf16(wh, xe[k0], a, 0,0,0);
      a = __builtin_amdgcn_mfma_f32_16x16x32_bf16(we, xh[k0], a, 0,0,0);
    }
    if(orow < N){
      if(ct < 4){
        ushort4 pk;
        unsigned u0 = __float_as_uint(a[0]);
        unsigned u1 = __float_as_uint(a[1]);
        unsigned u2 = __float_as_uint(a[2]);
        unsigned u3 = __float_as_uint(a[3]);
        pk.x = (unsigned short)((u0 + 0x7FFF + ((u0>>16)&1)) >> 16);
        pk.y = (unsigned short)((u1 + 0x7FFF + ((u1>>16)&1)) >> 16);
        pk.z = (unsigned short)((u2 + 0x7FFF + ((u2>>16)&1)) >> 16);
        pk.w = (unsigned short)((u3 + 0x7FFF + ((u3>>16)&1)) >> 16);
        *(ushort4*)(xlb + (size_t)orow*H + ct*16 + g*4) = pk;
      } else {
        *(float4*)(xr + (size_t)orow*H + (ct-4)*16 + g*4) =
            make_float4(a[0],a[1],a[2],a[3]);
      }
    }
  }
}

// K2: degree + shard-local rank (4-way sharded counters).
__global__ void k_degree(const int* __restrict__ ei, int E, int Etot, int N,
                         int* __restrict__ degs, int* __restrict__ rank){
  int i0 = (blockIdx.x*blockDim.x + threadIdx.x)*8;
  if(i0 >= Etot) return;
  if(i0 + 8 <= E){
    int4 da = *(const int4*)(ei + E + i0);
    int4 db = *(const int4*)(ei + E + i0 + 4);
    int r0 = atomicAdd(&degs[        da.x],1);
    int r1 = atomicAdd(&degs[        da.y],1);
    int r2 = atomicAdd(&degs[  N +   da.z],1);
    int r3 = atomicAdd(&degs[  N +   da.w],1);
    int r4 = atomicAdd(&degs[2*N +   db.x],1);
    int r5 = atomicAdd(&degs[2*N +   db.y],1);
    int r6 = atomicAdd(&degs[3*N +   db.z],1);
    int r7 = atomicAdd(&degs[3*N +   db.w],1);
    *(int4*)(rank + i0)     = make_int4(r0,r1,r2,r3);
    *(int4*)(rank + i0 + 4) = make_int4(r4,r5,r6,r7);
  } else if(i0 >= E && i0 + 8 <= Etot){
    int v = i0 - E;
    int r0 = atomicAdd(&degs[        v+0],1);
    int r1 = atomicAdd(&degs[        v+1],1);
    int r2 = atomicAdd(&degs[  N +   v+2],1);
    int r3 = atomicAdd(&degs[  N +   v+3],1);
    int r4 = atomicAdd(&degs[2*N +   v+4],1);
    int r5 = atomicAdd(&degs[2*N +   v+5],1);
    int r6 = atomicAdd(&degs[3*N +   v+6],1);
    int r7 = atomicAdd(&degs[3*N +   v+7],1);
    *(int4*)(rank + i0)     = make_int4(r0,r1,r2,r3);
    *(int4*)(rank + i0 + 4) = make_int4(r4,r5,r6,r7);
  } else {
    #pragma unroll
    for(int q=0;q<8;q++){
      int i = i0+q; if(i>=Etot) break;
      int dst = (i<E) ? ei[E+i] : (i-E);
      int s = q >> 1;
      rank[i] = atomicAdd(&degs[s*N + dst],1);
    }
  }
}

// K3: per-node total scan + in-place shard-exclusive offsets.
__global__ __launch_bounds__(256) void k_scan_a(int* __restrict__ degs, int n,
                                                int* __restrict__ rowptr,
                                                int* __restrict__ blocksum){
  __shared__ int wsum[4];
  int tid = threadIdx.x, lane = tid & 63, wid = tid >> 6;
  int idx = blockIdx.x*SCAN_CHUNK + tid*8;
  int v[8];
  if(idx + 8 <= n){
    int4 a0 = *(const int4*)(degs + idx),         a1 = *(const int4*)(degs + idx + 4);
    int4 b0 = *(const int4*)(degs + n + idx),     b1 = *(const int4*)(degs + n + idx + 4);
    int4 c0 = *(const int4*)(degs + 2*n + idx),   c1 = *(const int4*)(degs + 2*n + idx + 4);
    int4 e0 = *(const int4*)(degs + 3*n + idx),   e1 = *(const int4*)(degs + 3*n + idx + 4);
    *(int4*)(degs + n + idx)     = a0;
    *(int4*)(degs + n + idx + 4) = a1;
    int4 s20 = make_int4(a0.x+b0.x, a0.y+b0.y, a0.z+b0.z, a0.w+b0.w);
    int4 s21 = make_int4(a1.x+b1.x, a1.y+b1.y, a1.z+b1.z, a1.w+b1.w);
    *(int4*)(degs + 2*n + idx)     = s20;
    *(int4*)(degs + 2*n + idx + 4) = s21;
    int4 s30 = make_int4(s20.x+c0.x, s20.y+c0.y, s20.z+c0.z, s20.w+c0.w);
    int4 s31 = make_int4(s21.x+c1.x, s21.y+c1.y, s21.z+c1.z, s21.w+c1.w);
    *(int4*)(degs + 3*n + idx)     = s30;
    *(int4*)(degs + 3*n + idx + 4) = s31;
    v[0]=s30.x+e0.x; v[1]=s30.y+e0.y; v[2]=s30.z+e0.z; v[3]=s30.w+e0.w;
    v[4]=s31.x+e1.x; v[5]=s31.y+e1.y; v[6]=s31.z+e1.z; v[7]=s31.w+e1.w;
  } else {
    #pragma unroll
    for(int i=0;i<8;i++){
      int p = idx+i;
      if(p < n){
        int d0=degs[p], d1=degs[n+p], d2=degs[2*n+p], d3=degs[3*n+p];
        degs[n+p]=d0; degs[2*n+p]=d0+d1; degs[3*n+p]=d0+d1+d2;
        v[i]=d0+d1+d2+d3;
      } else v[i]=0;
    }
  }
  int pre[8]; int st=0;
  #pragma unroll
  for(int i=0;i<8;i++){ pre[i]=st; st+=v[i]; }
  int incl = st;
  #pragma unroll
  for(int o=1;o<64;o<<=1){ int u=__shfl_up(incl,o); if(lane>=o) incl+=u; }
  if(lane==63) wsum[wid]=incl;
  __syncthreads();
  if(tid==0){ int accu=0; for(int i=0;i<4;i++){ int t=wsum[i]; wsum[i]=accu; accu+=t; } }
  __syncthreads();
  int toff = wsum[wid] + incl - st;
  if(idx + 8 <= n){
    int4 o0 = make_int4(toff+pre[0],toff+pre[1],toff+pre[2],toff+pre[3]);
    int4 o1 = make_int4(toff+pre[4],toff+pre[5],toff+pre[6],toff+pre[7]);
    *(int4*)(rowptr+idx)=o0; *(int4*)(rowptr+idx+4)=o1;
  } else {
    #pragma unroll
    for(int i=0;i<8;i++) if(idx+i<n) rowptr[idx+i]=toff+pre[i];
  }
  if(tid==255){
    blocksum[blockIdx.x] = toff + st;
    if(blockIdx.x == gridDim.x-1) rowptr[n] = toff + st;
  }
}

// K4: CSR fill — no atomics (shard offsets via degs)
__global__ void k_fill(const int* __restrict__ ei, int E, int Etot, int N,
                       const int* __restrict__ rowptr,
                       const int* __restrict__ blocksum, int nscan,
                       const int* __restrict__ degs,
                       const int* __restrict__ rank, int* __restrict__ csr_src){
  __shared__ int bs[64];
  int tid = threadIdx.x;
  load_bs(blocksum, nscan, bs, tid);
  int i0 = (blockIdx.x*blockDim.x + tid)*8;
  if(i0 >= Etot) return;
  if(i0 + 8 <= E){
    int4 sa = *(const int4*)(ei + i0);
    int4 sb = *(const int4*)(ei + i0 + 4);
    int4 da = *(const int4*)(ei + E + i0);
    int4 db = *(const int4*)(ei + E + i0 + 4);
    int4 ra = *(const int4*)(rank + i0);
    int4 rb = *(const int4*)(rank + i0 + 4);
    csr_src[rowptr[da.x] + bs[da.x>>11] +                   ra.x] = sa.x;
    csr_src[rowptr[da.y] + bs[da.y>>11] +                   ra.y] = sa.y;
    csr_src[rowptr[da.z] + bs[da.z>>11] + degs[  N + da.z] + ra.z] = sa.z;
    csr_src[rowptr[da.w] + bs[da.w>>11] + degs[  N + da.w] + ra.w] = sa.w;
    csr_src[rowptr[db.x] + bs[db.x>>11] + degs[2*N + db.x] + rb.x] = sb.x;
    csr_src[rowptr[db.y] + bs[db.y>>11] + degs[2*N + db.y] + rb.y] = sb.y;
    csr_src[rowptr[db.z] + bs[db.z>>11] + degs[3*N + db.z] + rb.z] = sb.z;
    csr_src[rowptr[db.w] + bs[db.w>>11] + degs[3*N + db.w] + rb.w] = sb.w;
  } else if(i0 >= E && i0 + 8 <= Etot){
    int4 ra = *(const int4*)(rank + i0);
    int4 rb = *(const int4*)(rank + i0 + 4);
    int v = i0 - E;
    csr_src[rowptr[v+0] + bs[(v+0)>>11] +                    ra.x] = v+0;
    csr_src[rowptr[v+1] + bs[(v+1)>>11] +                    ra.y] = v+1;
    csr_src[rowptr[v+2] + bs[(v+2)>>11] + degs[  N + (v+2)] + ra.z] = v+2;
    csr_src[rowptr[v+3] + bs[(v+3)>>11] + degs[  N + (v+3)] + ra.w] = v+3;
    csr_src[rowptr[v+4] + bs[(v+4)>>11] + degs[2*N + (v+4)] + rb.x] = v+4;
    csr_src[rowptr[v+5] + bs[(v+5)>>11] + degs[2*N + (v+5)] + rb.y] = v+5;
    csr_src[rowptr[v+6] + bs[(v+6)>>11] + degs[3*N + (v+6)] + rb.z] = v+6;
    csr_src[rowptr[v+7] + bs[(v+7)>>11] + degs[3*N + (v+7)] + rb.w] = v+7;
  } else {
    #pragma unroll
    for(int q=0;q<8;q++){
      int i = i0+q; if(i>=Etot) break;
      int src, dst;
      if(i<E){ src = ei[i]; dst = ei[E+i]; } else { src = i-E; dst = i-E; }
      int s = q >> 1;
      int so = s ? degs[s*N + dst] : 0;
      csr_src[rowptr[dst] + bs[dst>>11] + so + rank[i]] = src;
    }
  }
}

// K5: fused layer-1 (no-max softmax).  16-lane group owns TWO consecutive nodes,
// walking both edge lists in lockstep chunks -> 16 gathers in flight per group
// (64/wave, 2x R16) for latency hiding; ushort4 gathers keep VGPR < 128.
__global__ __launch_bounds__(256) void k_node1f(
                         const int* __restrict__ rowptr, const int* __restrict__ blocksum,
                         int nscan, const int* __restrict__ csr_src,
                         const unsigned short* __restrict__ xlb, const float* __restrict__ xr,
                         const float* __restrict__ att, const float* __restrict__ b1,
                         const float* __restrict__ Wl2, const float* __restrict__ Wr2,
                         float* __restrict__ xl2, float* __restrict__ xr2, int N){
  __shared__ int bs[64];
  int tid = threadIdx.x;
  load_bs(blocksum, nscan, bs, tid);
  int grp = tid >> 4, gl = tid & 15;
  int nodeA = blockIdx.x*32 + grp*2;
  if(nodeA >= N) return;
  int nodeB = nodeA + 1;
  bool hasB = (nodeB < N);
  int f4 = gl*4;
  float4 attv = *(const float4*)(att + f4);
  float4 xrvA = *(const float4*)(xr + (size_t)nodeA*H + f4);
  float4 xrvB = hasB ? *(const float4*)(xr + (size_t)nodeB*H + f4) : make_float4(0,0,0,0);
  int sA = rowptr[nodeA]   + bs[nodeA>>11];
  int tA = rowptr[nodeA+1] + bs[(nodeA+1)>>11];
  int sB = 0, tB = 0;
  if(hasB){ sB = rowptr[nodeB] + bs[nodeB>>11]; tB = rowptr[nodeB+1] + bs[(nodeB+1)>>11]; }
  float dA=0.f, axA=0.f, ayA=0.f, azA=0.f, awA=0.f;
  float dB=0.f, axB=0.f, ayB=0.f, azB=0.f, awB=0.f;
  int tlA = tA - 1, tlB = (tB > sB) ? tB - 1 : 0;

  int kA = sA, kB = sB;
  while(kA < tA || kB < tB){
    int ksA[8], ksB[8];
    #pragma unroll
    for(int j=0;j<8;j++){
      int ka = kA + j; ksA[j] = (ka < tA) ? ka : tlA;
      int kb = kB + j; ksB[j] = (kb < tB) ? kb : tlB;
    }
    int ssA[8], ssB[8];
    #pragma unroll
    for(int j=0;j<8;j++) ssA[j] = csr_src[ksA[j]];
    #pragma unroll
    for(int j=0;j<8;j++) ssB[j] = csr_src[ksB[j]];
    ushort4 uvA[8], uvB[8];
    #pragma unroll
    for(int j=0;j<8;j++) uvA[j] = *(const ushort4*)(xlb + (size_t)ssA[j]*H + f4);
    #pragma unroll
    for(int j=0;j<8;j++) uvB[j] = *(const ushort4*)(xlb + (size_t)ssB[j]*H + f4);

    #pragma unroll
    for(int j=0;j<8;j++){
      float vx = __uint_as_float((unsigned)uvA[j].x << 16);
      float vy = __uint_as_float((unsigned)uvA[j].y << 16);
      float vz = __uint_as_float((unsigned)uvA[j].z << 16);
      float vw = __uint_as_float((unsigned)uvA[j].w << 16);
      float h0 = vx + xrvA.x, h1 = vy + xrvA.y, h2 = vz + xrvA.z, h3 = vw + xrvA.w;
      float l0 = (h0>0.f)? h0 : NEG_SLOPE*h0;
      float l1 = (h1>0.f)? h1 : NEG_SLOPE*h1;
      float l2 = (h2>0.f)? h2 : NEG_SLOPE*h2;
      float l3 = (h3>0.f)? h3 : NEG_SLOPE*h3;
      float e = l0*attv.x + l1*attv.y + l2*attv.z + l3*attv.w;
      #pragma unroll
      for(int o=1;o<16;o<<=1) e += __shfl_xor(e,o);
      float wj = (kA + j < tA) ? __expf(e) : 0.f;
      dA += wj; axA += wj*vx; ayA += wj*vy; azA += wj*vz; awA += wj*vw;
    }
    #pragma unroll
    for(int j=0;j<8;j++){
      float vx = __uint_as_float((unsigned)uvB[j].x << 16);
      float vy = __uint_as_float((unsigned)uvB[j].y << 16);
      float vz = __uint_as_float((unsigned)uvB[j].z << 16);
      float vw = __uint_as_float((unsigned)uvB[j].w << 16);
      float h0 = vx + xrvB.x, h1 = vy + xrvB.y, h2 = vz + xrvB.z, h3 = vw + xrvB.w;
      float l0 = (h0>0.f)? h0 : NEG_SLOPE*h0;
      float l1 = (h1>0.f)? h1 : NEG_SLOPE*h1;
      float l2 = (h2>0.f)? h2 : NEG_SLOPE*h2;
      float l3 = (h3>0.f)? h3 : NEG_SLOPE*h3;
      float e = l0*attv.x + l1*attv.y + l2*attv.z + l3*attv.w;
      #pragma unroll
      for(int o=1;o<16;o<<=1) e += __shfl_xor(e,o);
      float wj = (kB + j < tB) ? __expf(e) : 0.f;
      dB += wj; axB += wj*vx; ayB += wj*vy; azB += wj*vz; awB += wj*vw;
    }
    kA += 8; kB += 8;
  }

  float4 bv = *(const float4*)(b1 + f4);
  // epilogue for node A
  {
    float inv = 1.f/(dA + EPS);
    float h0 = axA*inv + bv.x, h1 = ayA*inv + bv.y;
    float h2 = azA*inv + bv.z, h3 = awA*inv + bv.w;
    float p0 = h0*Wl2[(f4+0)*FOUT+0] + h1*Wl2[(f4+1)*FOUT+0] + h2*Wl2[(f4+2)*FOUT+0] + h3*Wl2[(f4+3)*FOUT+0];
    float p1 = h0*Wl2[(f4+0)*FOUT+1] + h1*Wl2[(f4+1)*FOUT+1] + h2*Wl2[(f4+2)*FOUT+1] + h3*Wl2[(f4+3)*FOUT+1];
    float p2 = h0*Wr2[(f4+0)*FOUT+0] + h1*Wr2[(f4+1)*FOUT+0] + h2*Wr2[(f4+2)*FOUT+0] + h3*Wr2[(f4+3)*FOUT+0];
    float p3 = h0*Wr2[(f4+0)*FOUT+1] + h1*Wr2[(f4+1)*FOUT+1] + h2*Wr2[(f4+2)*FOUT+1] + h3*Wr2[(f4+3)*FOUT+1];
    #pragma unroll
    for(int o=1;o<16;o<<=1){
      p0 += __shfl_xor(p0,o); p1 += __shfl_xor(p1,o);
      p2 += __shfl_xor(p2,o); p3 += __shfl_xor(p3,o);
    }
    if(gl==0){
      *(float2*)(xl2 + nodeA*2) = make_float2(p0,p1);
      *(float2*)(xr2 + nodeA*2) = make_float2(p2,p3);
    }
  }
  // epilogue for node B
  if(hasB){
    float inv = 1.f/(dB + EPS);
    float h0 = axB*inv + bv.x, h1 = ayB*inv + bv.y;
    float h2 = azB*inv + bv.z, h3 = awB*inv + bv.w;
    float p0 = h0*Wl2[(f4+0)*FOUT+0] + h1*Wl2[(f4+1)*FOUT+0] + h2*Wl2[(f4+2)*FOUT+0] + h3*Wl2[(f4+3)*FOUT+0];
    float p1 = h0*Wl2[(f4+0)*FOUT+1] + h1*Wl2[(f4+1)*FOUT+1] + h2*Wl2[(f4+2)*FOUT+1] + h3*Wl2[(f4+3)*FOUT+1];
    float p2 = h0*Wr2[(f4+0)*FOUT+0] + h1*Wr2[(f4+1)*FOUT+0] + h2*Wr2[(f4+2)*FOUT+0] + h3*Wr2[(f4+3)*FOUT+0];
    float p3 = h0*Wr2[(f4+0)*FOUT+1] + h1*Wr2[(f4+1)*FOUT+1] + h2*Wr2[(f4+2)*FOUT+1] + h3*Wr2[(f4+3)*FOUT+1];
    #pragma unroll
    for(int o=1;o<16;o<<=1){
      p0 += __shfl_xor(p0,o); p1 += __shfl_xor(p1,o);
      p2 += __shfl_xor(p2,o); p3 += __shfl_xor(p3,o);
    }
    if(gl==0){
      *(float2*)(xl2 + nodeB*2) = make_float2(p0,p1);
      *(float2*)(xr2 + nodeB*2) = make_float2(p2,p3);
    }
  }
}

// K6: layer-2 full conv, single pass (no-max), 16-lane group per node (R16).
__global__ void k_node2(const int* __restrict__ rowptr, const int* __restrict__ blocksum,
                        int nscan, const int* __restrict__ csr_src,
                        const float* __restrict__ xl2, const float* __restrict__ xr2,
                        const float* __restrict__ att2, const float* __restrict__ b2,
                        float* __restrict__ out, int N){
  __shared__ int bs[64];
  int tid = threadIdx.x;
  load_bs(blocksum, nscan, bs, tid);
  int node = blockIdx.x*16 + (tid>>4);
  int gl = tid & 15;
  if(node >= N) return;
  int s = rowptr[node]   + bs[node>>11];
  int t = rowptr[node+1] + bs[(node+1)>>11];
  float2 xrv = *(const float2*)(xr2 + node*2);
  float a0 = att2[0], a1 = att2[1];
  float den=0.f, n0=0.f, n1=0.f;
  for(int k=s+gl; k<t; k+=16){
    int src = csr_src[k];
    float2 xs = *(const float2*)(xl2 + src*2);
    float h0 = xs.x + xrv.x, h1 = xs.y + xrv.y;
    float l0 = (h0>0.f)? h0 : NEG_SLOPE*h0;
    float l1 = (h1>0.f)? h1 : NEG_SLOPE*h1;
    float ex = __expf(l0*a0 + l1*a1);
    den += ex; n0 += ex*xs.x; n1 += ex*xs.y;
  }
  #pragma unroll
  for(int o=1;o<16;o<<=1){
    den += __shfl_xor(den,o);
    n0  += __shfl_xor(n0,o);
    n1  += __shfl_xor(n1,o);
  }
  if(gl==0){
    float inv = 1.f/(den + EPS);
    out[node*2+0] = n0*inv + b2[0];
    out[node*2+1] = n1*inv + b2[1];
  }
}

extern "C" void kernel_launch(void* const* d_in, const int* in_sizes, int n_in,
                              void* d_out, int out_size, void* d_ws, size_t ws_size,
                              hipStream_t stream){
  const float* x    = (const float*)d_in[0];
  const int*   ei   = (const int*)d_in[1];
  const float* Wl1  = (const float*)d_in[2];
  const float* Wr1  = (const float*)d_in[3];
  const float* att1 = (const float*)d_in[4];
  const float* b1   = (const float*)d_in[5];
  const float* Wl2  = (const float*)d_in[6];
  const float* Wr2  = (const float*)d_in[7];
  const float* att2 = (const float*)d_in[8];
  const float* b2   = (const float*)d_in[9];
  int N = in_sizes[0]/FIN;
  int E = in_sizes[1]/2;
  int Etot = E + N;
  int nscan = (N + SCAN_CHUNK - 1) / SCAN_CHUNK;   // 25 for N=50000 (<=64 required)
  int noct  = (Etot + 7) / 8;
  int ZB = (4*N + 255) / 256;                      // zero 4 shard arrays
  int GDO = (noct + 255) / 256;

  char* w = (char*)d_ws;
  size_t off = 0;
  auto alloc = [&](size_t bytes)->void*{
    void* p = w + off;
    off = (off + bytes + 255) & ~(size_t)255;
    return p;
  };
  float* xr1     = (float*)alloc((size_t)N*H*4);
  unsigned short* xlb = (unsigned short*)alloc((size_t)N*H*2);
  int*   csr_src = (int*)  alloc((size_t)Etot*4);
  int*   rank    = (int*)  alloc((size_t)Etot*4);
  int*   degs    = (int*)  alloc((size_t)4*N*4);   // 4 shards
  int*   rowptr  = (int*)  alloc((size_t)(N+1)*4);
  int*   blocksum= (int*)  alloc((size_t)64*4);
  float* xl2     = (float*)alloc((size_t)N*2*4);
  float* xr2     = (float*)alloc((size_t)N*2*4);
  unsigned short* pWh = (unsigned short*)alloc((size_t)2048*8*2);
  unsigned short* pWe = (unsigned short*)alloc((size_t)2048*8*2);

  k_prep<<<ZB+8, 256, 0, stream>>>(degs, 4*N, ZB, Wl1, Wr1, pWh, pWe);
  k_gemm_mfma<<<(N+63)/64, 256, 0, stream>>>(x, pWh, pWe, xr1, xlb, N);
  k_degree<<<GDO,256,0,stream>>>(ei, E, Etot, N, degs, rank);
  k_scan_a<<<nscan,256,0,stream>>>(degs, N, rowptr, blocksum);
  k_fill<<<GDO,256,0,stream>>>(ei, E, Etot, N, rowptr, blocksum, nscan, degs, rank, csr_src);
  k_node1f<<<(N+31)/32, 256, 0, stream>>>(rowptr, blocksum, nscan, csr_src,
                                          xlb, xr1, att1, b1, Wl2, Wr2, xl2, xr2, N);
  k_node2<<<(N+15)/16, 256, 0, stream>>>(rowptr, blocksum, nscan, csr_src,
                                         xl2, xr2, att2, b2, (float*)d_out, N);
}

// Round 19
// 122.671 us; speedup vs baseline: 1.1312x; 1.1312x over previous
//
#include <hip/hip_runtime.h>
#include <math.h>

#define FIN 128
#define H 64
#define FOUT 2
#define NEG_SLOPE 0.2f
#define EPS 1e-16f

#define SCAN_CHUNK 2048   // elements per scan_a block (256 thr * 8)

typedef __attribute__((ext_vector_type(8))) short s8v;   // 8 bf16 (4 VGPR)
typedef __attribute__((ext_vector_type(4))) float f4v;   // MFMA acc

// Preamble: exclusive scan of blocksum[0..nscan) into LDS bs[] (nscan <= 64).
__device__ __forceinline__ void load_bs(const int* __restrict__ blocksum, int nscan,
                                        int* bs, int tid){
  if(tid < 64){
    int v = (tid < nscan)? blocksum[tid] : 0;
    int incl = v;
    #pragma unroll
    for(int o=1;o<64;o<<=1){ int u=__shfl_up(incl,o); if(tid>=o) incl+=u; }
    bs[tid] = incl - v;
  }
  __syncthreads();
}

// K0: fused [zero degs (4 shards)] + [pack W into MFMA fragments, split hi/lo bf16].
__global__ void k_prep(int* __restrict__ degs, int N4, int ZB,
                       const float* __restrict__ Wl, const float* __restrict__ Wr,
                       unsigned short* __restrict__ pWh, unsigned short* __restrict__ pWe){
  int b = blockIdx.x;
  if(b < ZB){
    int i = b*256 + threadIdx.x;
    if(i < N4) degs[i] = 0;
    return;
  }
  int idx = (b - ZB)*256 + threadIdx.x;     // (ct*4+k0)*64 + lane, < 2048
  int lane = idx & 63;
  int ctk  = idx >> 6;
  int k0   = (ctk & 3) * 32;
  int ct   = ctk >> 2;
  int c    = ct*16 + (lane & 15);
  int kb   = k0 + (lane >> 4)*8;
  const float* Wp = (c < 64) ? (Wl + c) : (Wr + (c - 64));
  #pragma unroll
  for(int j=0;j<8;j++){
    float v = Wp[(size_t)(kb + j)*H];
    unsigned u = __float_as_uint(v);
    unsigned short hb = (unsigned short)(u >> 16);
    float hv = __uint_as_float(((unsigned)hb) << 16);
    float ev = v - hv;
    unsigned short eb = (unsigned short)(__float_as_uint(ev) >> 16);
    pWh[(size_t)idx*8 + j] = hb;
    pWe[(size_t)idx*8 + j] = eb;
  }
}

// K1: MFMA GEMM, swapped operands: D = W^T x; float4/ushort4 stores.
__global__ __launch_bounds__(256) void k_gemm_mfma(
    const float* __restrict__ x,
    const unsigned short* __restrict__ pWh, const unsigned short* __restrict__ pWe,
    float* __restrict__ xr, unsigned short* __restrict__ xlb, int N){
  int tid = threadIdx.x;
  int lane = tid & 63, wid = tid >> 6;
  int rowbase = blockIdx.x*64 + wid*16;
  int r = lane & 15, g = lane >> 4;

  int arow = rowbase + r; if(arow > N-1) arow = N-1;
  const float* xrow = x + (size_t)arow*FIN;
  int orow = rowbase + r;

  s8v xh[4], xe[4];
  #pragma unroll
  for(int k0=0;k0<4;k0++){
    float4 va = *(const float4*)(xrow + k0*32 + g*8);
    float4 vb = *(const float4*)(xrow + k0*32 + g*8 + 4);
    float xs_[8] = {va.x,va.y,va.z,va.w,vb.x,vb.y,vb.z,vb.w};
    #pragma unroll
    for(int j=0;j<8;j++){
      unsigned u = __float_as_uint(xs_[j]);
      unsigned short hb = (unsigned short)(u >> 16);
      xh[k0][j] = (short)hb;
      float ev = xs_[j] - __uint_as_float(((unsigned)hb) << 16);
      xe[k0][j] = (short)(unsigned short)(__float_as_uint(ev) >> 16);
    }
  }

  #pragma unroll 2
  for(int ct=0;ct<8;ct++){
    f4v a = (f4v){0.f,0.f,0.f,0.f};
    #pragma unroll
    for(int k0=0;k0<4;k0++){
      size_t boff = ((size_t)(ct*4 + k0)*64 + lane)*8;
      s8v wh = *(const s8v*)(pWh + boff);
      s8v we = *(const s8v*)(pWe + boff);
      a = __builtin_amdgcn_mfma_f32_16x16x32_bf16(wh, xh[k0], a, 0,0,0);
      a = __builtin_amdgcn_mfma_f32_16x16x32_bf16(wh, xe[k0], a, 0,0,0);
      a = __builtin_amdgcn_mfma_f32_16x16x32_bf16(we, xh[k0], a, 0,0,0);
    }
    if(orow < N){
      if(ct < 4){
        ushort4 pk;
        unsigned u0 = __float_as_uint(a[0]);
        unsigned u1 = __float_as_uint(a[1]);
        unsigned u2 = __float_as_uint(a[2]);
        unsigned u3 = __float_as_uint(a[3]);
        pk.x = (unsigned short)((u0 + 0x7FFF + ((u0>>16)&1)) >> 16);
        pk.y = (unsigned short)((u1 + 0x7FFF + ((u1>>16)&1)) >> 16);
        pk.z = (unsigned short)((u2 + 0x7FFF + ((u2>>16)&1)) >> 16);
        pk.w = (unsigned short)((u3 + 0x7FFF + ((u3>>16)&1)) >> 16);
        *(ushort4*)(xlb + (size_t)orow*H + ct*16 + g*4) = pk;
      } else {
        *(float4*)(xr + (size_t)orow*H + (ct-4)*16 + g*4) =
            make_float4(a[0],a[1],a[2],a[3]);
      }
    }
  }
}

// K2: degree + shard-local rank (4-way sharded counters).
__global__ void k_degree(const int* __restrict__ ei, int E, int Etot, int N,
                         int* __restrict__ degs, int* __restrict__ rank){
  int i0 = (blockIdx.x*blockDim.x + threadIdx.x)*8;
  if(i0 >= Etot) return;
  if(i0 + 8 <= E){
    int4 da = *(const int4*)(ei + E + i0);
    int4 db = *(const int4*)(ei + E + i0 + 4);
    int r0 = atomicAdd(&degs[        da.x],1);
    int r1 = atomicAdd(&degs[        da.y],1);
    int r2 = atomicAdd(&degs[  N +   da.z],1);
    int r3 = atomicAdd(&degs[  N +   da.w],1);
    int r4 = atomicAdd(&degs[2*N +   db.x],1);
    int r5 = atomicAdd(&degs[2*N +   db.y],1);
    int r6 = atomicAdd(&degs[3*N +   db.z],1);
    int r7 = atomicAdd(&degs[3*N +   db.w],1);
    *(int4*)(rank + i0)     = make_int4(r0,r1,r2,r3);
    *(int4*)(rank + i0 + 4) = make_int4(r4,r5,r6,r7);
  } else if(i0 >= E && i0 + 8 <= Etot){
    int v = i0 - E;
    int r0 = atomicAdd(&degs[        v+0],1);
    int r1 = atomicAdd(&degs[        v+1],1);
    int r2 = atomicAdd(&degs[  N +   v+2],1);
    int r3 = atomicAdd(&degs[  N +   v+3],1);
    int r4 = atomicAdd(&degs[2*N +   v+4],1);
    int r5 = atomicAdd(&degs[2*N +   v+5],1);
    int r6 = atomicAdd(&degs[3*N +   v+6],1);
    int r7 = atomicAdd(&degs[3*N +   v+7],1);
    *(int4*)(rank + i0)     = make_int4(r0,r1,r2,r3);
    *(int4*)(rank + i0 + 4) = make_int4(r4,r5,r6,r7);
  } else {
    #pragma unroll
    for(int q=0;q<8;q++){
      int i = i0+q; if(i>=Etot) break;
      int dst = (i<E) ? ei[E+i] : (i-E);
      int s = q >> 1;
      rank[i] = atomicAdd(&degs[s*N + dst],1);
    }
  }
}

// K3: per-node total scan + in-place shard-exclusive offsets.
__global__ __launch_bounds__(256) void k_scan_a(int* __restrict__ degs, int n,
                                                int* __restrict__ rowptr,
                                                int* __restrict__ blocksum){
  __shared__ int wsum[4];
  int tid = threadIdx.x, lane = tid & 63, wid = tid >> 6;
  int idx = blockIdx.x*SCAN_CHUNK + tid*8;
  int v[8];
  if(idx + 8 <= n){
    int4 a0 = *(const int4*)(degs + idx),         a1 = *(const int4*)(degs + idx + 4);
    int4 b0 = *(const int4*)(degs + n + idx),     b1 = *(const int4*)(degs + n + idx + 4);
    int4 c0 = *(const int4*)(degs + 2*n + idx),   c1 = *(const int4*)(degs + 2*n + idx + 4);
    int4 e0 = *(const int4*)(degs + 3*n + idx),   e1 = *(const int4*)(degs + 3*n + idx + 4);
    *(int4*)(degs + n + idx)     = a0;
    *(int4*)(degs + n + idx + 4) = a1;
    int4 s20 = make_int4(a0.x+b0.x, a0.y+b0.y, a0.z+b0.z, a0.w+b0.w);
    int4 s21 = make_int4(a1.x+b1.x, a1.y+b1.y, a1.z+b1.z, a1.w+b1.w);
    *(int4*)(degs + 2*n + idx)     = s20;
    *(int4*)(degs + 2*n + idx + 4) = s21;
    int4 s30 = make_int4(s20.x+c0.x, s20.y+c0.y, s20.z+c0.z, s20.w+c0.w);
    int4 s31 = make_int4(s21.x+c1.x, s21.y+c1.y, s21.z+c1.z, s21.w+c1.w);
    *(int4*)(degs + 3*n + idx)     = s30;
    *(int4*)(degs + 3*n + idx + 4) = s31;
    v[0]=s30.x+e0.x; v[1]=s30.y+e0.y; v[2]=s30.z+e0.z; v[3]=s30.w+e0.w;
    v[4]=s31.x+e1.x; v[5]=s31.y+e1.y; v[6]=s31.z+e1.z; v[7]=s31.w+e1.w;
  } else {
    #pragma unroll
    for(int i=0;i<8;i++){
      int p = idx+i;
      if(p < n){
        int d0=degs[p], d1=degs[n+p], d2=degs[2*n+p], d3=degs[3*n+p];
        degs[n+p]=d0; degs[2*n+p]=d0+d1; degs[3*n+p]=d0+d1+d2;
        v[i]=d0+d1+d2+d3;
      } else v[i]=0;
    }
  }
  int pre[8]; int st=0;
  #pragma unroll
  for(int i=0;i<8;i++){ pre[i]=st; st+=v[i]; }
  int incl = st;
  #pragma unroll
  for(int o=1;o<64;o<<=1){ int u=__shfl_up(incl,o); if(lane>=o) incl+=u; }
  if(lane==63) wsum[wid]=incl;
  __syncthreads();
  if(tid==0){ int accu=0; for(int i=0;i<4;i++){ int t=wsum[i]; wsum[i]=accu; accu+=t; } }
  __syncthreads();
  int toff = wsum[wid] + incl - st;
  if(idx + 8 <= n){
    int4 o0 = make_int4(toff+pre[0],toff+pre[1],toff+pre[2],toff+pre[3]);
    int4 o1 = make_int4(toff+pre[4],toff+pre[5],toff+pre[6],toff+pre[7]);
    *(int4*)(rowptr+idx)=o0; *(int4*)(rowptr+idx+4)=o1;
  } else {
    #pragma unroll
    for(int i=0;i<8;i++) if(idx+i<n) rowptr[idx+i]=toff+pre[i];
  }
  if(tid==255){
    blocksum[blockIdx.x] = toff + st;
    if(blockIdx.x == gridDim.x-1) rowptr[n] = toff + st;
  }
}

// K4: CSR fill — no atomics (shard offsets via degs)
__global__ void k_fill(const int* __restrict__ ei, int E, int Etot, int N,
                       const int* __restrict__ rowptr,
                       const int* __restrict__ blocksum, int nscan,
                       const int* __restrict__ degs,
                       const int* __restrict__ rank, int* __restrict__ csr_src){
  __shared__ int bs[64];
  int tid = threadIdx.x;
  load_bs(blocksum, nscan, bs, tid);
  int i0 = (blockIdx.x*blockDim.x + tid)*8;
  if(i0 >= Etot) return;
  if(i0 + 8 <= E){
    int4 sa = *(const int4*)(ei + i0);
    int4 sb = *(const int4*)(ei + i0 + 4);
    int4 da = *(const int4*)(ei + E + i0);
    int4 db = *(const int4*)(ei + E + i0 + 4);
    int4 ra = *(const int4*)(rank + i0);
    int4 rb = *(const int4*)(rank + i0 + 4);
    csr_src[rowptr[da.x] + bs[da.x>>11] +                   ra.x] = sa.x;
    csr_src[rowptr[da.y] + bs[da.y>>11] +                   ra.y] = sa.y;
    csr_src[rowptr[da.z] + bs[da.z>>11] + degs[  N + da.z] + ra.z] = sa.z;
    csr_src[rowptr[da.w] + bs[da.w>>11] + degs[  N + da.w] + ra.w] = sa.w;
    csr_src[rowptr[db.x] + bs[db.x>>11] + degs[2*N + db.x] + rb.x] = sb.x;
    csr_src[rowptr[db.y] + bs[db.y>>11] + degs[2*N + db.y] + rb.y] = sb.y;
    csr_src[rowptr[db.z] + bs[db.z>>11] + degs[3*N + db.z] + rb.z] = sb.z;
    csr_src[rowptr[db.w] + bs[db.w>>11] + degs[3*N + db.w] + rb.w] = sb.w;
  } else if(i0 >= E && i0 + 8 <= Etot){
    int4 ra = *(const int4*)(rank + i0);
    int4 rb = *(const int4*)(rank + i0 + 4);
    int v = i0 - E;
    csr_src[rowptr[v+0] + bs[(v+0)>>11] +                    ra.x] = v+0;
    csr_src[rowptr[v+1] + bs[(v+1)>>11] +                    ra.y] = v+1;
    csr_src[rowptr[v+2] + bs[(v+2)>>11] + degs[  N + (v+2)] + ra.z] = v+2;
    csr_src[rowptr[v+3] + bs[(v+3)>>11] + degs[  N + (v+3)] + ra.w] = v+3;
    csr_src[rowptr[v+4] + bs[(v+4)>>11] + degs[2*N + (v+4)] + rb.x] = v+4;
    csr_src[rowptr[v+5] + bs[(v+5)>>11] + degs[2*N + (v+5)] + rb.y] = v+5;
    csr_src[rowptr[v+6] + bs[(v+6)>>11] + degs[3*N + (v+6)] + rb.z] = v+6;
    csr_src[rowptr[v+7] + bs[(v+7)>>11] + degs[3*N + (v+7)] + rb.w] = v+7;
  } else {
    #pragma unroll
    for(int q=0;q<8;q++){
      int i = i0+q; if(i>=Etot) break;
      int src, dst;
      if(i<E){ src = ei[i]; dst = ei[E+i]; } else { src = i-E; dst = i-E; }
      int s = q >> 1;
      int so = s ? degs[s*N + dst] : 0;
      csr_src[rowptr[dst] + bs[dst>>11] + so + rank[i]] = src;
    }
  }
}

// K5: fused layer-1 (no-max softmax).  16-lane group per node, 4 nodes/wave.
// Chunk-of-8 edges, bf16 gathers (8B/lane/edge), natural node order (coalesced I/O).
__global__ void k_node1f(const int* __restrict__ rowptr, const int* __restrict__ blocksum,
                         int nscan, const int* __restrict__ csr_src,
                         const unsigned short* __restrict__ xlb, const float* __restrict__ xr,
                         const float* __restrict__ att, const float* __restrict__ b1,
                         const float* __restrict__ Wl2, const float* __restrict__ Wr2,
                         float* __restrict__ xl2, float* __restrict__ xr2, int N){
  __shared__ int bs[64];
  int tid = threadIdx.x;
  load_bs(blocksum, nscan, bs, tid);
  int node = blockIdx.x*16 + (tid>>4);
  int gl = tid & 15;
  if(node >= N) return;
  int f4 = gl*4;
  float4 attv = *(const float4*)(att + f4);
  float4 xrv  = *(const float4*)(xr + (size_t)node*H + f4);
  int s = rowptr[node]   + bs[node>>11];
  int t = rowptr[node+1] + bs[(node+1)>>11];
  float d = 0.f;
  float ax=0.f, ay=0.f, az=0.f, aw=0.f;

  for(int k=s; k<t; k+=8){
    int tl = t - 1;
    int ks[8]; float4 xv[8]; float msk[8];
    #pragma unroll
    for(int j=0;j<8;j++){
      int kj = k + j;
      ks[j] = (kj < t) ? kj : tl;
      msk[j] = (kj < t) ? 1.f : 0.f;
    }
    int ss[8];
    #pragma unroll
    for(int j=0;j<8;j++) ss[j] = csr_src[ks[j]];
    #pragma unroll
    for(int j=0;j<8;j++){
      ushort4 uv = *(const ushort4*)(xlb + (size_t)ss[j]*H + f4);
      xv[j].x = __uint_as_float((unsigned)uv.x << 16);
      xv[j].y = __uint_as_float((unsigned)uv.y << 16);
      xv[j].z = __uint_as_float((unsigned)uv.z << 16);
      xv[j].w = __uint_as_float((unsigned)uv.w << 16);
    }
    #pragma unroll
    for(int j=0;j<8;j++){
      float h0 = xv[j].x + xrv.x, h1 = xv[j].y + xrv.y;
      float h2 = xv[j].z + xrv.z, h3 = xv[j].w + xrv.w;
      float l0 = (h0>0.f)? h0 : NEG_SLOPE*h0;
      float l1 = (h1>0.f)? h1 : NEG_SLOPE*h1;
      float l2 = (h2>0.f)? h2 : NEG_SLOPE*h2;
      float l3 = (h3>0.f)? h3 : NEG_SLOPE*h3;
      float e = l0*attv.x + l1*attv.y + l2*attv.z + l3*attv.w;
      #pragma unroll
      for(int o=1;o<16;o<<=1) e += __shfl_xor(e,o);
      float w = msk[j] * __expf(e);
      d  += w;
      ax += w*xv[j].x; ay += w*xv[j].y; az += w*xv[j].z; aw += w*xv[j].w;
    }
  }

  float inv = 1.f/(d + EPS);
  float4 bv = *(const float4*)(b1 + f4);
  float h0 = ax*inv + bv.x, h1 = ay*inv + bv.y;
  float h2 = az*inv + bv.z, h3 = aw*inv + bv.w;
  float p0 = h0*Wl2[(f4+0)*FOUT+0] + h1*Wl2[(f4+1)*FOUT+0] + h2*Wl2[(f4+2)*FOUT+0] + h3*Wl2[(f4+3)*FOUT+0];
  float p1 = h0*Wl2[(f4+0)*FOUT+1] + h1*Wl2[(f4+1)*FOUT+1] + h2*Wl2[(f4+2)*FOUT+1] + h3*Wl2[(f4+3)*FOUT+1];
  float p2 = h0*Wr2[(f4+0)*FOUT+0] + h1*Wr2[(f4+1)*FOUT+0] + h2*Wr2[(f4+2)*FOUT+0] + h3*Wr2[(f4+3)*FOUT+0];
  float p3 = h0*Wr2[(f4+0)*FOUT+1] + h1*Wr2[(f4+1)*FOUT+1] + h2*Wr2[(f4+2)*FOUT+1] + h3*Wr2[(f4+3)*FOUT+1];
  #pragma unroll
  for(int o=1;o<16;o<<=1){
    p0 += __shfl_xor(p0,o); p1 += __shfl_xor(p1,o);
    p2 += __shfl_xor(p2,o); p3 += __shfl_xor(p3,o);
  }
  if(gl==0){
    *(float2*)(xl2 + node*2) = make_float2(p0,p1);
    *(float2*)(xr2 + node*2) = make_float2(p2,p3);
  }
}

// K6: layer-2 full conv, single pass (no-max), 16-lane group per node
__global__ void k_node2(const int* __restrict__ rowptr, const int* __restrict__ blocksum,
                        int nscan, const int* __restrict__ csr_src,
                        const float* __restrict__ xl2, const float* __restrict__ xr2,
                        const float* __restrict__ att2, const float* __restrict__ b2,
                        float* __restrict__ out, int N){
  __shared__ int bs[64];
  int tid = threadIdx.x;
  load_bs(blocksum, nscan, bs, tid);
  int node = blockIdx.x*16 + (tid>>4);
  int gl = tid & 15;
  if(node >= N) return;
  int s = rowptr[node]   + bs[node>>11];
  int t = rowptr[node+1] + bs[(node+1)>>11];
  float2 xrv = *(const float2*)(xr2 + node*2);
  float a0 = att2[0], a1 = att2[1];
  float den=0.f, n0=0.f, n1=0.f;
  for(int k=s+gl; k<t; k+=16){
    int src = csr_src[k];
    float2 xs = *(const float2*)(xl2 + src*2);
    float h0 = xs.x + xrv.x, h1 = xs.y + xrv.y;
    float l0 = (h0>0.f)? h0 : NEG_SLOPE*h0;
    float l1 = (h1>0.f)? h1 : NEG_SLOPE*h1;
    float ex = __expf(l0*a0 + l1*a1);
    den += ex; n0 += ex*xs.x; n1 += ex*xs.y;
  }
  #pragma unroll
  for(int o=1;o<16;o<<=1){
    den += __shfl_xor(den,o);
    n0  += __shfl_xor(n0,o);
    n1  += __shfl_xor(n1,o);
  }
  if(gl==0){
    float inv = 1.f/(den + EPS);
    out[node*2+0] = n0*inv + b2[0];
    out[node*2+1] = n1*inv + b2[1];
  }
}

extern "C" void kernel_launch(void* const* d_in, const int* in_sizes, int n_in,
                              void* d_out, int out_size, void* d_ws, size_t ws_size,
                              hipStream_t stream){
  const float* x    = (const float*)d_in[0];
  const int*   ei   = (const int*)d_in[1];
  const float* Wl1  = (const float*)d_in[2];
  const float* Wr1  = (const float*)d_in[3];
  const float* att1 = (const float*)d_in[4];
  const float* b1   = (const float*)d_in[5];
  const float* Wl2  = (const float*)d_in[6];
  const float* Wr2  = (const float*)d_in[7];
  const float* att2 = (const float*)d_in[8];
  const float* b2   = (const float*)d_in[9];
  int N = in_sizes[0]/FIN;
  int E = in_sizes[1]/2;
  int Etot = E + N;
  int nscan = (N + SCAN_CHUNK - 1) / SCAN_CHUNK;   // 25 for N=50000 (<=64 required)
  int noct  = (Etot + 7) / 8;
  int ZB = (4*N + 255) / 256;                      // zero 4 shard arrays
  int GDO = (noct + 255) / 256;

  char* w = (char*)d_ws;
  size_t off = 0;
  auto alloc = [&](size_t bytes)->void*{
    void* p = w + off;
    off = (off + bytes + 255) & ~(size_t)255;
    return p;
  };
  float* xr1     = (float*)alloc((size_t)N*H*4);
  unsigned short* xlb = (unsigned short*)alloc((size_t)N*H*2);
  int*   csr_src = (int*)  alloc((size_t)Etot*4);
  int*   rank    = (int*)  alloc((size_t)Etot*4);
  int*   degs    = (int*)  alloc((size_t)4*N*4);   // 4 shards
  int*   rowptr  = (int*)  alloc((size_t)(N+1)*4);
  int*   blocksum= (int*)  alloc((size_t)64*4);
  float* xl2     = (float*)alloc((size_t)N*2*4);
  float* xr2     = (float*)alloc((size_t)N*2*4);
  unsigned short* pWh = (unsigned short*)alloc((size_t)2048*8*2);
  unsigned short* pWe = (unsigned short*)alloc((size_t)2048*8*2);

  k_prep<<<ZB+8, 256, 0, stream>>>(degs, 4*N, ZB, Wl1, Wr1, pWh, pWe);
  k_gemm_mfma<<<(N+63)/64, 256, 0, stream>>>(x, pWh, pWe, xr1, xlb, N);
  k_degree<<<GDO,256,0,stream>>>(ei, E, Etot, N, degs, rank);
  k_scan_a<<<nscan,256,0,stream>>>(degs, N, rowptr, blocksum);
  k_fill<<<GDO,256,0,stream>>>(ei, E, Etot, N, rowptr, blocksum, nscan, degs, rank, csr_src);
  k_node1f<<<(N+15)/16, 256, 0, stream>>>(rowptr, blocksum, nscan, csr_src,
                                          xlb, xr1, att1, b1, Wl2, Wr2, xl2, xr2, N);
  k_node2<<<(N+15)/16, 256, 0, stream>>>(rowptr, blocksum, nscan, csr_src,
                                         xl2, xr2, att2, b2, (float*)d_out, N);
}